// Round 17
// baseline (107.311 us; speedup 1.0000x reference)
//
#include <hip/hip_runtime.h>

// SSM DPLR kernel: K[h,l] = 2*Re(C_h . dA_h^l . dB_h), dA = diag(g) + q r^T.
// R20 (= R19 x 2 domains): R16-R19 quadruple proved chain time = per-wave
// step work x steps (hop structure irrelevant). R17 halved steps but doubled
// per-wave work (4-wave domains, 16 rows/wave) -> neutral. R20 halves steps
// at CONSTANT per-wave work: 16 waves, TWO independent 8-wave flag domains,
// each identical to R19's proven protocol (8 rows/wave, 1 counter hop,
// replicated reduce, double-buffered prt):
//   domain A (waves 0..7):  C (M128)^i        -> even rows, 15 steps
//   domain B (waves 8..15): (C M64)(M128)^i   -> odd rows, 16 steps + rebuild
// M128 closed form via extended tau (R6b-HW-verified). Chain sync area lives
// in the dead G region of Abuf; X-rebuild deferred post-chain (sigma in regs).
//   - 1024 threads, grid 256, amdgpu_waves_per_eu(4,4); LDS 55808 B
//   - wave0: tau128-solve + dual Horner; wave1: sigma-solve (X after chain)
//   - all Mk/idmk indexing compile-time; diag via select (R10)

#define LL 2048

struct C2 { float re, im; };

__device__ __forceinline__ C2 cmul(C2 a, C2 b){ return {a.re*b.re - a.im*b.im, a.re*b.im + a.im*b.re}; }
__device__ __forceinline__ C2 cadd(C2 a, C2 b){ return {a.re+b.re, a.im+b.im}; }
__device__ __forceinline__ C2 csub(C2 a, C2 b){ return {a.re-b.re, a.im-b.im}; }
__device__ __forceinline__ C2 cinv(C2 a){ float s=1.0f/(a.re*a.re+a.im*a.im); return {a.re*s, -a.im*s}; }
__device__ __forceinline__ C2 cscale(float s, C2 a){ return {s*a.re, s*a.im}; }
__device__ __forceinline__ C2 ld2(float2 v){ return {v.x, v.y}; }
__device__ __forceinline__ float2 st2(C2 v){ return make_float2(v.re, v.im); }

template<int CTRL>
__device__ __forceinline__ float dpp_add(float x){
  int t = __builtin_amdgcn_update_dpp(0, __float_as_int(x), CTRL, 0xF, 0xF, true);
  return x + __int_as_float(t);
}
// lane 63 ends with the full 64-lane sum
__device__ __forceinline__ float wave_sum63(float x){
  x = dpp_add<0xB1>(x);   // quad_perm xor1
  x = dpp_add<0x4E>(x);   // quad_perm xor2
  x = dpp_add<0x124>(x);  // row_ror:4
  x = dpp_add<0x128>(x);  // row_ror:8
  x = dpp_add<0x142>(x);  // row_bcast:15
  x = dpp_add<0x143>(x);  // row_bcast:31
  return x;
}
__device__ __forceinline__ float bcast63(float x){
  return __int_as_float(__builtin_amdgcn_readlane(__float_as_int(x), 63));
}
__device__ __forceinline__ float rdlane(float v, int l){
  return __int_as_float(__builtin_amdgcn_readlane(__float_as_int(v), l));
}
// D[m] = S[m-1], lane0 <- 0   (wave_shr:1 = 0x138)
__device__ __forceinline__ float shr1(float x){
  return __int_as_float(__builtin_amdgcn_update_dpp(0, __float_as_int(x), 0x138, 0xF, 0xF, true));
}
// insert scalar s (SGPR, from readlane) into lane 0 of v: v_cndmask
__device__ __forceinline__ float ins0(float v, float s, int lane){
  return (lane == 0) ? s : v;
}

// 2-wide triangular-Toeplitz solve (length 64): v_j = rhs_j + sum_{i<j} w_{j-1-i} v_i.
__device__ __forceinline__ void tri_solve64(const C2 wl, C2 va, const int lane,
                                            float& so_re, float& so_im)
{
    C2 wsh = { shr1(wl.re), shr1(wl.im) };      // w_{m-1}, lane0 = 0
    const float w0r = rdlane(wl.re, 0);
    const float w0i = rdlane(wl.im, 0);
    so_re = 0.0f; so_im = 0.0f;
    for (int j = 0; j < 64; j += 2) {
        const float s0r = rdlane(va.re, j);
        const float s0i = rdlane(va.im, j);
        const float v1r = rdlane(va.re, j + 1);
        const float v1i = rdlane(va.im, j + 1);
        const float s1r = v1r + (w0r*s0r - w0i*s0i);
        const float s1i = v1i + (w0r*s0i + w0i*s0r);
        if (lane == j)     { so_re = s0r; so_im = s0i; }
        if (lane == j + 1) { so_re = s1r; so_im = s1i; }
        const C2 wsh1 = { shr1(wsh.re), shr1(wsh.im) };   // w_{m-2-j}
        va.re += wsh.re*s0r - wsh.im*s0i;
        va.im += wsh.re*s0i + wsh.im*s0r;
        va.re += wsh1.re*s1r - wsh1.im*s1i;
        va.im += wsh1.re*s1i + wsh1.im*s1r;
        wsh.re = shr1(wsh1.re);
        wsh.im = shr1(wsh1.im);
    }
}

// 2-wide extended solve (length 128): state split lo (j=0..63) / hi (j=64..127).
// On return: tlo lane j = tau_j, thi lane c = tau_{64+c}.   (R6b-verified)
__device__ __forceinline__ void tri_solve128(const C2 wlo, const C2 whi, const int lane,
                                             C2& tlo, C2& thi)
{
    C2 valo = wlo, vahi = whi;                  // rhs = w (tau solve)
    C2 wsl = { shr1(wlo.re), shr1(wlo.im) };    // w_{m-1}
    C2 wsh;                                     // w_{63+m'}
    {
        const float br = rdlane(wlo.re, 63), bi = rdlane(wlo.im, 63);
        wsh.re = ins0(shr1(whi.re), br, lane);
        wsh.im = ins0(shr1(whi.im), bi, lane);
    }
    const float w0r = rdlane(wlo.re, 0);
    const float w0i = rdlane(wlo.im, 0);
    tlo = {0,0}; thi = {0,0};
    // lo region: sources j = 0..63
    for (int j = 0; j < 64; j += 2) {
        const float s0r = rdlane(valo.re, j);
        const float s0i = rdlane(valo.im, j);
        const float v1r = rdlane(valo.re, j + 1);
        const float v1i = rdlane(valo.im, j + 1);
        const float s1r = v1r + (w0r*s0r - w0i*s0i);
        const float s1i = v1i + (w0r*s0i + w0i*s0r);
        if (lane == j)     { tlo.re = s0r; tlo.im = s0i; }
        if (lane == j + 1) { tlo.re = s1r; tlo.im = s1i; }
        const C2 wsl1 = { shr1(wsl.re), shr1(wsl.im) };           // w_{m-2-j}
        C2 wsh1;
        {
            const float br = rdlane(wsl.re, 63), bi = rdlane(wsl.im, 63);  // w_{62-j}
            wsh1.re = ins0(shr1(wsh.re), br, lane);
            wsh1.im = ins0(shr1(wsh.im), bi, lane);
        }
        valo.re += wsl.re*s0r - wsl.im*s0i + wsl1.re*s1r - wsl1.im*s1i;
        valo.im += wsl.re*s0i + wsl.im*s0r + wsl1.re*s1i + wsl1.im*s1r;
        vahi.re += wsh.re*s0r - wsh.im*s0i + wsh1.re*s1r - wsh1.im*s1i;
        vahi.im += wsh.re*s0i + wsh.im*s0r + wsh1.re*s1i + wsh1.im*s1r;
        wsl.re = shr1(wsl1.re); wsl.im = shr1(wsl1.im);
        {
            const float br = rdlane(wsl1.re, 63), bi = rdlane(wsl1.im, 63); // w_{61-j}
            wsh.re = ins0(shr1(wsh1.re), br, lane);
            wsh.im = ins0(shr1(wsh1.im), bi, lane);
        }
    }
    // hi region: sources j = 64..127; lo coefficients exhausted, shift-ins are 0.
    for (int j = 64; j < 128; j += 2) {
        const int jr = j - 64;
        const float s0r = rdlane(vahi.re, jr);
        const float s0i = rdlane(vahi.im, jr);
        const float v1r = rdlane(vahi.re, jr + 1);
        const float v1i = rdlane(vahi.im, jr + 1);
        const float s1r = v1r + (w0r*s0r - w0i*s0i);
        const float s1i = v1i + (w0r*s0i + w0i*s0r);
        if (lane == jr)     { thi.re = s0r; thi.im = s0i; }
        if (lane == jr + 1) { thi.re = s1r; thi.im = s1i; }
        const C2 wsh1 = { shr1(wsh.re), shr1(wsh.im) };
        vahi.re += wsh.re*s0r - wsh.im*s0i + wsh1.re*s1r - wsh1.im*s1i;
        vahi.im += wsh.re*s0i + wsh.im*s0r + wsh1.re*s1i + wsh1.im*s1r;
        wsh.re = shr1(wsh1.re);
        wsh.im = shr1(wsh1.im);
    }
}

__global__ __launch_bounds__(1024)
__attribute__((amdgpu_waves_per_eu(4, 4)))
void ssm_dplr_kernel(
    const float* __restrict__ A_real, const float* __restrict__ A_imag,
    const float* __restrict__ B_real, const float* __restrict__ B_imag,
    const float* __restrict__ P_real, const float* __restrict__ P_imag,
    const float* __restrict__ C_real, const float* __restrict__ C_imag,
    const float* __restrict__ log_dt, float* __restrict__ out)
{
    const int h    = blockIdx.x;
    const int t    = threadIdx.x;
    const int lane = t & 63;
    const int wid  = t >> 6;         // wave 0..15

    extern __shared__ char sm[];
    float2* Abuf = (float2*)sm;               // 64x64: G, then chain sync, then X [32 KB]
    // chain-phase occupants INSIDE Abuf (G dead after transpose-sums):
    float2* cbufAll = (float2*)sm;             // 16 x 64 per-wave private [ 8 KB]
    float2* prtC    = (float2*)(sm + 8192);    // [2][16][64] partials     [16 KB]
    int*    cntA    = (int*)(sm + 24576);      // 32 step counters domain A
    int*    cntB    = cntA + 32;               // 32 step counters domain B
    float2* Cs   = (float2*)(sm + 32768);     // 32x64 Y rows                [16 KB]
    // transpose-sum partials alias Cs (dead at that phase), two passes:
    float2* tw   = Cs;                        // 16x64
    float2* ta   = Cs + 1024;                 // 16x64
    // persistent smalls @49152 (live through the chain):
    float2* gA   = (float2*)(sm + 49152);
    float2* qA   = gA + 64;
    float2* g64A = gA + 128;
    float2* TgA  = gA + 192;   // T64(g)
    float2* TpA  = gA + 256;   // T64'(g)
    float2* T1gA = gA + 320;   // T128(g)
    float2* T1pA = gA + 384;   // T128'(g)
    // transient smalls @52736 (dead after serial window):
    float2* rqA  = (float2*)(sm + 52736);
    float2* rxA  = rqA + 64;
    float2* reA  = rqA + 128;  // rq * g64
    float2* wvA  = rqA + 192;  // w_0..63
    float2* avA  = rqA + 256;  // a_0..63
    float2* weA  = rqA + 320;  // w_64..127
    // LDS total: 55808 B

    // ---------------- setup (every wave redundantly, per-lane n = lane) ----------------
    const int idx = h * 64 + lane;
    const float dt = expf(log_dt[h]);
    const float c  = 0.5f * dt;

    const C2 lam = { -A_real[idx], -A_imag[idx] };
    const C2 p   = {  P_real[idx],  P_imag[idx] };
    const C2 Bv  = {  B_real[idx],  B_imag[idx] };
    const C2 Cv  = {  C_real[idx],  C_imag[idx] };
    const C2 pc  = { p.re, -p.im };

    const C2 d = cinv(C2{ 1.0f - c*lam.re, -c*lam.im });
    const C2 g = cmul(d, C2{ 1.0f + c*lam.re, c*lam.im });   // diag of dA

    // Sherman-Morrison scalars via DPP wave sums
    C2 sv = cscale(p.re*p.re + p.im*p.im, d);
    C2 uv = cmul(cmul(d, pc), Bv);
    sv.re = bcast63(wave_sum63(sv.re)); sv.im = bcast63(wave_sum63(sv.im));
    uv.re = bcast63(wave_sum63(uv.re)); uv.im = bcast63(wave_sum63(uv.im));

    const C2 beta  = cscale(c, cinv(C2{ 1.0f + c*sv.re, c*sv.im }));
    const C2 bs    = cmul(beta, sv);
    const C2 gamma = { -c*(1.0f - bs.re), c*bs.im };

    const C2 q  = cmul(d, p);
    const C2 r  = cmul(pc, csub(gamma, cmul(beta, g)));
    const C2 x0 = cscale(dt, csub(cmul(d, Bv), cmul(cmul(beta, uv), q)));  // dB

    // power chain
    const C2 g2  = cmul(g,  g);
    const C2 g4  = cmul(g2, g2);
    const C2 g8  = cmul(g4, g4);
    const C2 g16 = cmul(g8, g8);
    const C2 g32 = cmul(g16,g16);
    const C2 g64 = cmul(g32,g32);

    if (wid == 0) {
        const C2 rq = cmul(r, q);
        gA[lane]   = st2(g);
        qA[lane]   = st2(q);
        g64A[lane] = st2(g64);
        rqA[lane]  = st2(rq);
        rxA[lane]  = st2(cmul(r, x0));
        reA[lane]  = st2(cmul(rq, g64));
    }
    __syncthreads();

    // ---------------- G-gen: G[j][n] = g_n^j, rows j in [4w, 4w+4) ----------------
    {
        C2 cur = {1.0f, 0.0f};
        if (wid & 1) cur = g4;
        if (wid & 2) cur = cmul(cur, g8);
        if (wid & 4) cur = cmul(cur, g16);
        if (wid & 8) cur = cmul(cur, g32);          // g^(4*wid)
        #pragma unroll
        for (int jj = 0; jj < 4; ++jj) {
            const int j = 4*wid + jj;
            Abuf[j*64 + ((lane + j) & 63)] = st2(cur);   // rotated columns
            cur = cmul(cur, g);
        }
    }
    __syncthreads();

    // ---------------- transpose-sums, pass 1: w_j, a_j (lane = j) ----------------
    {
        C2 accw = {0,0}, acca = {0,0};
        #pragma unroll
        for (int kk = 0; kk < 4; ++kk) {
            const int n = 4*wid + kk;
            const C2 Gv = ld2(Abuf[lane*64 + ((n + lane) & 63)]);
            const C2 fq = ld2(rqA[n]);      // uniform
            const C2 fx = ld2(rxA[n]);      // uniform
            accw = cadd(accw, cmul(Gv, fq));
            acca = cadd(acca, cmul(Gv, fx));
        }
        tw[wid*64 + lane] = st2(accw);
        ta[wid*64 + lane] = st2(acca);
    }
    __syncthreads();
    if (t < 64) {
        C2 sw = {0,0}, sa = {0,0};
        #pragma unroll
        for (int w2 = 0; w2 < 16; ++w2) {
            sw = cadd(sw, ld2(tw[w2*64 + t]));
            sa = cadd(sa, ld2(ta[w2*64 + t]));
        }
        wvA[t] = st2(sw);
        avA[t] = st2(sa);
    }
    __syncthreads();

    // ---------------- transpose-sums, pass 2: we_j = w_{64+j} ----------------
    {
        C2 acce = {0,0};
        #pragma unroll
        for (int kk = 0; kk < 4; ++kk) {
            const int n = 4*wid + kk;
            const C2 Gv = ld2(Abuf[lane*64 + ((n + lane) & 63)]);
            const C2 fe = ld2(reA[n]);      // uniform
            acce = cadd(acce, cmul(Gv, fe));
        }
        tw[wid*64 + lane] = st2(acce);      // reuse tw
    }
    __syncthreads();
    if (t < 64) {
        C2 se = {0,0};
        #pragma unroll
        for (int w2 = 0; w2 < 16; ++w2) {
            se = cadd(se, ld2(tw[w2*64 + t]));
        }
        weA[t] = st2(se);
    }
    __syncthreads();

    // ---------------- serial window ----------------
    // all waves: division prep for their 8 M rows (base 8*(wid&7))
    // wave0: tau128-solve + dual Horner -> T64/T64'/T128/T128'
    // wave1: sigma-solve ONLY (sigma kept in regs; X rebuilt after chain)
    // wave2: zero both counter arrays (Abuf/G dead now)
    const bool isB = (wid >= 8);
    const int  dw  = wid & 7;              // wave index within domain
    C2 idmk[8];
    #pragma unroll
    for (int kk = 0; kk < 8; ++kk) {
        idmk[kk] = cinv(csub(ld2(gA[8*dw + kk]), g));   // k==lane -> inf/NaN, deselected
    }
    float sg_re = 0.0f, sg_im = 0.0f;      // wave1's sigma (persists through chain)
    if (wid == 0) {
        C2 tlo, thi;
        tri_solve128(ld2(wvA[lane]), ld2(weA[lane]), lane, tlo, thi);
        // P-Horner over tau_0..62 ; Q-Horner over tau_63..126 (interleaved chains)
        C2 pp = { rdlane(tlo.re, 0),  rdlane(tlo.im, 0)  };
        C2 dd = {0,0};
        C2 qq = { rdlane(tlo.re, 63), rdlane(tlo.im, 63) };   // tau_63
        C2 qd = {0,0};
        for (int i = 1; i <= 63; ++i) {
            if (i <= 62) {
                const C2 ti = { rdlane(tlo.re, i), rdlane(tlo.im, i) };
                dd = cadd(cmul(dd, g), pp);
                pp = cadd(cmul(pp, g), ti);
            }
            const C2 tq = { rdlane(thi.re, i-1), rdlane(thi.im, i-1) };  // tau_{63+i}
            qd = cadd(cmul(qd, g), qq);
            qq = cadd(cmul(qq, g), tq);
        }
        const C2 T64v = cmul(g, pp);              // T64(g)
        const C2 T64d = cadd(pp, cmul(g, dd));    // T64'(g)
        // T128(z) = z^64 T64(z) + z Q(z);  T128' = 64 z^63 T64 + z^64 T64' + Q + z Q'
        const C2 g63h  = cmul(g64, cinv(g));
        const C2 T128v = cadd(cmul(g64, T64v), cmul(g, qq));
        const C2 T128d = cadd(cadd(cscale(64.0f, cmul(g63h, T64v)), cmul(g64, T64d)),
                              cadd(qq, cmul(g, qd)));
        TgA[lane]  = st2(T64v);
        TpA[lane]  = st2(T64d);
        T1gA[lane] = st2(T128v);
        T1pA[lane] = st2(T128d);
    } else if (wid == 1) {
        tri_solve64(ld2(wvA[lane]), ld2(avA[lane]), lane, sg_re, sg_im);   // sigma
    } else if (wid == 2) {
        if (lane < 32) cntA[lane] = 0;
        else           cntB[lane - 32] = 0;
    }
    __syncthreads();   // transient smalls die; Abuf sync area initialized

    // ---------------- M build (regs, rows k = 8dw..8dw+7) ----------------
    // M_t[k][m] = d_km g^t_k + q_k r_m [ (g^t_k - g^t_m) + (T_t(g_k)-T_t(g_m)) ] / (g_k - g_m)
    // M_t[k][k] = g^t_k + q_k r_k ( t g_k^{t-1} + T_t'(g_k) )
    C2 Mk[8];
    auto buildM = [&](bool p128){
        const C2 gt   = p128 ? cmul(g64, g64) : g64;                    // g^t (lane m)
        const C2 Ttm  = p128 ? ld2(T1gA[lane]) : ld2(TgA[lane]);
        const C2 Tp   = p128 ? ld2(T1pA[lane]) : ld2(TpA[lane]);
        const C2 g63  = cmul(g64, cinv(g));
        const C2 gtm1 = p128 ? cmul(g64, g63) : g63;                    // g^{t-1}
        const C2 S    = cmul(r, cadd(cscale(p128 ? 128.0f : 64.0f, gtm1), Tp));
        const C2 diagv = cadd(gt, cmul(q, S));    // value for M[lane][lane]
        #pragma unroll
        for (int kk = 0; kk < 8; ++kk) {
            const int k = 8*dw + kk;
            const C2 qn   = ld2(qA[k]);            // uniform reads
            const C2 g64n = ld2(g64A[k]);
            const C2 gtn  = p128 ? cmul(g64n, g64n) : g64n;
            const C2 Ttn  = p128 ? ld2(T1gA[k]) : ld2(TgA[k]);
            const C2 num  = cmul(r, cadd(csub(gtn, gt), csub(Ttn, Ttm)));
            const C2 off  = cmul(cmul(qn, num), idmk[kk]);   // kk compile-time
            const bool isd = (lane == k);
            Mk[kk].re = isd ? diagv.re : off.re;
            Mk[kk].im = isd ? diagv.im : off.im;
        }
    };
    if (!isB) buildM(true);            // domain A: M128
    else      buildM(false);           // domain B: M64 (seed), rebuilt after step 0
    if (wid == 0) Cs[lane] = st2(Cv);  // output row 0 = C
    __syncthreads();                   // M regs + counters + Cs[0] visible

    // ---------------- dual replicated-reduce chains (independent domains) --------
    {
        float2* cb = cbufAll + wid*64;             // per-wave PRIVATE broadcast buffer
        const float4* cb4 = (const float4*)cb;
        volatile int* vcnt = isB ? (volatile int*)cntB : (volatile int*)cntA;
        int* cnt = isB ? cntB : cntA;
        const int dbase = isB ? 8 : 0;             // prt slot base for this domain
        cb[lane] = st2(Cv);                        // step input C_0 = C

        const int s0 = isB ? 0 : 1;                // B has the M64 seed step
        for (int s = s0; s <= 15; ++s) {
            const int buf = s & 1;
            // produce: this wave's 8-row slice (reads OWN cb)
            const float4 ya = cb4[4*dw + 0];       // c_{8dw},   c_{8dw+1}
            const float4 yb = cb4[4*dw + 1];       // c_{8dw+2}, c_{8dw+3}
            const float4 yc = cb4[4*dw + 2];
            const float4 yd = cb4[4*dw + 3];
            float ar = 0.0f, ai = 0.0f;
            ar += ya.x*Mk[0].re - ya.y*Mk[0].im;  ai += ya.x*Mk[0].im + ya.y*Mk[0].re;
            ar += ya.z*Mk[1].re - ya.w*Mk[1].im;  ai += ya.z*Mk[1].im + ya.w*Mk[1].re;
            ar += yb.x*Mk[2].re - yb.y*Mk[2].im;  ai += yb.x*Mk[2].im + yb.y*Mk[2].re;
            ar += yb.z*Mk[3].re - yb.w*Mk[3].im;  ai += yb.z*Mk[3].im + yb.w*Mk[3].re;
            ar += yc.x*Mk[4].re - yc.y*Mk[4].im;  ai += yc.x*Mk[4].im + yc.y*Mk[4].re;
            ar += yc.z*Mk[5].re - yc.w*Mk[5].im;  ai += yc.z*Mk[5].im + yc.w*Mk[5].re;
            ar += yd.x*Mk[6].re - yd.y*Mk[6].im;  ai += yd.x*Mk[6].im + yd.y*Mk[6].re;
            ar += yd.z*Mk[7].re - yd.w*Mk[7].im;  ai += yd.z*Mk[7].im + yd.w*Mk[7].re;
            prtC[buf*1024 + (dbase + dw)*64 + lane] = make_float2(ar, ai);
            __threadfence_block();                 // partial visible before counting
            if (lane == 0) atomicAdd(&cnt[s], 1);
            while (vcnt[s] < 8) { }                // all 8 partials in (own domain)
            __asm__ volatile("" ::: "memory");
            // replicated reduce: every wave builds the full new vector itself
            C2 nc = {0,0};
            #pragma unroll
            for (int w2 = 0; w2 < 8; ++w2) {
                const float2 pv = prtC[buf*1024 + (dbase + w2)*64 + lane];
                nc.re += pv.x; nc.im += pv.y;
            }
            cb[lane] = st2(nc);                    // own copy for next step (in-order DS)
            if (!isB) {
                if (wid == 0) Cs[(2*s)*64 + lane] = st2(nc);       // even row 2s
            } else {
                if (wid == 8) Cs[(2*s + 1)*64 + lane] = st2(nc);   // odd row 2s+1
                if (s == 0) buildM(true);          // rebuild Mk as M128 after seed
            }
        }
    }
    __syncthreads();

    // ---------------- wave1: X rebuild into Abuf (chain sync area is dead) --------
    if (wid == 1) {
        // X_0 = dB; X_{j+1} = g.*X_j + sigma_j * q
        C2 x = x0;
        for (int j = 0; j < 64; ++j) {
            Abuf[j*64 + ((lane + j) & 63)] = st2(x);
            const float sjr = rdlane(sg_re, j);
            const float sji = rdlane(sg_im, j);
            const float nr = g.re*x.re - g.im*x.im + sjr*q.re - sji*q.im;
            const float ni = g.re*x.im + g.im*x.re + sjr*q.im + sji*q.re;
            x.re = nr; x.im = ni;
        }
    }
    __syncthreads();

    // ---------------- output: rows r0 = 2*wid, r1 = 2*wid+1 ----------------
    {
        const int r0 = 2*wid, r1 = 2*wid + 1;
        float a0 = 0.0f, a1 = 0.0f;
        #pragma unroll 8
        for (int n = 0; n < 64; ++n) {
            const float2 xv = Abuf[lane*64 + ((n + lane) & 63)];
            const float2 c0 = Cs[r0*64 + n];    // uniform
            const float2 c1 = Cs[r1*64 + n];    // uniform
            a0 += c0.x*xv.x - c0.y*xv.y;
            a1 += c1.x*xv.x - c1.y*xv.y;
        }
        float* outh = out + h * LL;
        outh[r0*64 + lane] = 2.0f * a0;
        outh[r1*64 + lane] = 2.0f * a1;
    }
}

extern "C" void kernel_launch(void* const* d_in, const int* in_sizes, int n_in,
                              void* d_out, int out_size, void* d_ws, size_t ws_size,
                              hipStream_t stream) {
    const float* A_real = (const float*)d_in[0];
    const float* A_imag = (const float*)d_in[1];
    const float* B_real = (const float*)d_in[2];
    const float* B_imag = (const float*)d_in[3];
    const float* P_real = (const float*)d_in[4];
    const float* P_imag = (const float*)d_in[5];
    const float* C_real = (const float*)d_in[6];
    const float* C_imag = (const float*)d_in[7];
    const float* log_dt = (const float*)d_in[8];
    float* out = (float*)d_out;

    const size_t lds = 55808;
    ssm_dplr_kernel<<<256, 1024, lds, stream>>>(
        A_real, A_imag, B_real, B_imag, P_real, P_imag,
        C_real, C_imag, log_dt, out);
}